// Round 5
// baseline (153.174 us; speedup 1.0000x reference)
//
#include <hip/hip_runtime.h>

// B=2, T=2048, C=1024, H=16, D=64
// qkv row-major [4096, 3072]; y row-major [4096, 1024]; out fp32 [4096,1024]
//
// Time ledger (R11/R12 probes, µs): timed window ~148 = 2 poison fills (~86, harness,
// not optimizable) + conv ~9 + G1 ~30 + attn ~2-3 + G2 ~16 + gaps ~4.
// R13 (burst-issue + vmcnt(0) drain at phase 3) was NEUTRAL — consistent with m218:
// phase-split with drain-0 == no phase-split. R14: counted vmcnt. Stage issues for
// tile t+1 staggered across tile t's phases, order pinned (sched_barrier 0x38F =
// VMEM may not cross); W1=vmcnt(2) at tile end (first-5 = needs of next phase 0),
// W2=vmcnt(4) before phase 2 (oldest-2 = A1,A3 of current tile). Queue never drains.
// Barriers: 2 per K-tile (after W1, after W2) — cross-wave DMA visibility only.

typedef _Float16 h8 __attribute__((ext_vector_type(8)));
typedef _Float16 h4 __attribute__((ext_vector_type(4)));
typedef float f4 __attribute__((ext_vector_type(4)));

// ---- cross-lane helpers (16-lane DPP rows) ----
template <int CTRL>
__device__ __forceinline__ float dpp_shr_self(float x) {  // shifted-in lanes read own x
  int xi = __builtin_bit_cast(int, x);
  return __builtin_bit_cast(float,
      __builtin_amdgcn_update_dpp(xi, xi, CTRL, 0xF, 0xF, false));
}
__device__ __forceinline__ float scan16_max(float x) {  // inclusive max-scan over 16 lanes
  x = fmaxf(x, dpp_shr_self<0x111>(x));
  x = fmaxf(x, dpp_shr_self<0x112>(x));
  x = fmaxf(x, dpp_shr_self<0x114>(x));
  x = fmaxf(x, dpp_shr_self<0x118>(x));
  return x;
}
__device__ __forceinline__ float bcast15(float x) {  // lane15 of each 16-lane group -> group
  return __builtin_bit_cast(float,
      __builtin_amdgcn_ds_swizzle(__builtin_bit_cast(int, x), 0x01F0));
}

// async global->LDS, 16 B per lane. LDS dest is wave-uniform base + lane*16 (HW rule);
// per-lane GLOBAL address is free, which is how the XOR swizzle is applied (source side).
__device__ __forceinline__ void gload_lds16(const _Float16* src, _Float16* dst_lds) {
  __builtin_amdgcn_global_load_lds(
      (const __attribute__((address_space(1))) void*)src,
      (__attribute__((address_space(3))) void*)dst_lds, 16, 0, 0);
}

// counted waits on the wave's outstanding global_load_lds queue (in-order completion).
// "memory" clobber pins all memory ops; sched_barrier(0) additionally pins reg-only ops
// (rule #18).
__device__ __forceinline__ void vm_wait0() {
  asm volatile("s_waitcnt vmcnt(0)" ::: "memory");
  __builtin_amdgcn_sched_barrier(0);
}
__device__ __forceinline__ void vm_wait2() {
  asm volatile("s_waitcnt vmcnt(2)" ::: "memory");
  __builtin_amdgcn_sched_barrier(0);
}
__device__ __forceinline__ void vm_wait4() {
  asm volatile("s_waitcnt vmcnt(4)" ::: "memory");
  __builtin_amdgcn_sched_barrier(0);
}
// Pin VMEM issue order across this point; ALU/VALU/SALU/MFMA/DS may cross (0x38F).
__device__ __forceinline__ void vmem_order_fence() {
  __builtin_amdgcn_sched_barrier(0x38F);
}

// One kernel converts all three fp32 inputs to fp16. Slot = 4 floats.
__global__ __launch_bounds__(256) void convert_all_kernel(const float* __restrict__ x,
                                                          const float* __restrict__ Wa,
                                                          const float* __restrict__ Wp,
                                                          _Float16* __restrict__ xh,
                                                          _Float16* __restrict__ wah,
                                                          _Float16* __restrict__ wph) {
  int i = blockIdx.x * 256 + threadIdx.x;
  const float* src;
  _Float16* dst;
  int off;
  if (i < 1048576) { src = x; dst = xh; off = i; }
  else if (i < 1048576 + 786432) { src = Wa; dst = wah; off = i - 1048576; }
  else { src = Wp; dst = wph; off = i - (1048576 + 786432); }
  f4 v = *(const f4*)(src + (size_t)off * 4);
  h4 o;
  for (int j = 0; j < 4; ++j) o[j] = (_Float16)v[j];
  *(h4*)(dst + (size_t)off * 4) = o;
}

// ===================== GEMM1: counted-vmcnt staged pipeline =======================
// C[M,N] = A[M,K] @ B[N,K]^T, fp16 in/out fp16, fp32 accum.
// BM=256, BN=192, BK=64, 512 threads = 8 waves (2m x 4n), per-wave out 128x48.
// Grid = 16*16 = 256 = 1 block/CU. LDS 112 KB (2 tile buffers).
// Stage chunks (per wave, 1 gload each): A0..A3 = A rows [j*64,+64), B0..B2 likewise.
// Phase p consumes af rows wm*128+[p*32,+32) (A-chunk p/2 for wm=0, 2+p/2 for wm=1)
// and all B at phase 0. Issue slots for tile t+1: p0{B0,B1} p1{B2,A0} p2{A2} p3{A1,A3}.
// First-5 issued == needed at next tile's p0; last-2 == needed at its p2.
// XOR swizzle (both sides, R10-verified): source chunk lsc^(row&7), read chunk
// (ks*4+q4)^(row&7) -> fragment ds_read_b128 2-way (free).
__global__ __launch_bounds__(512, 2) void gemm1_pipe_kernel(const _Float16* __restrict__ A,
                                                            const _Float16* __restrict__ B,
                                                            _Float16* __restrict__ C,
                                                            int M, int N, int K) {
  __shared__ _Float16 As[2][256 * 64];  // 64 KB
  __shared__ _Float16 Bs[2][192 * 64];  // 48 KB
  const int tid = threadIdx.x;
  const int wave = tid >> 6, lane = tid & 63;
  const int wm = wave >> 2, wn = wave & 3;
  const int l16 = lane & 15, q4 = lane >> 4;
  const int lrow = lane >> 3, lsc = lane & 7;

  // XCD swizzle: 256 blocks, 8 XCDs x 32; each XCD owns n-stripe of 2.
  const int xcd = blockIdx.x & 7;
  const int idx = blockIdx.x >> 3;
  const int n_blk = xcd * 2 + (idx & 1);
  const int m_blk = idx >> 1;
  const int m0 = m_blk * 256, n0 = n_blk * 192;

  f4 acc[8][3] = {};

  const int NT = K >> 6;  // 16

  auto stageA = [&](int buf, int j, int k0) {
    const int row = j * 64 + wave * 8 + lrow;
    gload_lds16(A + (size_t)(m0 + row) * K + k0 + (lsc ^ (row & 7)) * 8,
                &As[buf][(j * 64 + wave * 8) * 64]);
  };
  auto stageB = [&](int buf, int j, int k0) {
    const int row = j * 64 + wave * 8 + lrow;
    gload_lds16(B + (size_t)(n0 + row) * K + k0 + (lsc ^ (row & 7)) * 8,
                &Bs[buf][(j * 64 + wave * 8) * 64]);
  };

  // ---- prologue: stage K-tile 0 into buffer 0 (same order as steady state) ----
  stageB(0, 0, 0); stageB(0, 1, 0); stageB(0, 2, 0); stageA(0, 0, 0); stageA(0, 2, 0);
  vmem_order_fence();
  stageA(0, 1, 0); stageA(0, 3, 0);
  vm_wait2();                       // first-5 done (B*, A0, A2); A1,A3 in flight
  __builtin_amdgcn_s_barrier();

  int cur = 0;
  for (int kt = 0; kt < NT; ++kt) {
    const bool more = (kt + 1 < NT);
    const int nxt = cur ^ 1;
    const int k1 = (kt + 1) << 6;

    // B-fragments for this K-tile (rows staged & visible per W1-barrier)
    h8 bf[3][2];
#pragma unroll
    for (int ni = 0; ni < 3; ++ni)
#pragma unroll
      for (int ks = 0; ks < 2; ++ks) {
        const int row = wn * 48 + ni * 16 + l16;
        bf[ni][ks] = *(const h8*)(&Bs[cur][row * 64 + ((ks * 4 + q4) ^ (row & 7)) * 8]);
      }

#pragma unroll
    for (int P = 0; P < 4; ++P) {
      // stage issues for tile t+1 (cross-phase order pinned; pair-internal order free)
      if (more) {
        if (P == 0) { stageB(nxt, 0, k1); stageB(nxt, 1, k1); }
        if (P == 1) { stageB(nxt, 2, k1); stageA(nxt, 0, k1); }
        if (P == 2) { stageA(nxt, 2, k1); }
        if (P == 3) { stageA(nxt, 1, k1); stageA(nxt, 3, k1); }
        vmem_order_fence();
      }
      if (P == 2) {
        // W2: previous tile's A1,A3 (this wave's 2 oldest) done; 4 newer stay in flight
        if (more) vm_wait4(); else vm_wait0();
        __builtin_amdgcn_s_barrier();   // cross-wave visibility of those DMAs
      }
      h8 af[2][2];
#pragma unroll
      for (int i = 0; i < 2; ++i)
#pragma unroll
        for (int ks = 0; ks < 2; ++ks) {
          const int row = wm * 128 + (P * 2 + i) * 16 + l16;
          af[i][ks] = *(const h8*)(&As[cur][row * 64 + ((ks * 4 + q4) ^ (row & 7)) * 8]);
        }
      __builtin_amdgcn_s_setprio(1);
#pragma unroll
      for (int ks = 0; ks < 2; ++ks)
#pragma unroll
        for (int i = 0; i < 2; ++i)
#pragma unroll
          for (int ni = 0; ni < 3; ++ni)
            acc[P * 2 + i][ni] = __builtin_amdgcn_mfma_f32_16x16x32_f16(
                af[i][ks], bf[ni][ks], acc[P * 2 + i][ni], 0, 0, 0);
      __builtin_amdgcn_s_setprio(0);
    }
    // W1: next tile's first-5 (B*, A0, A2) done; its A1,A3 remain in flight.
    if (more) vm_wait2();
    __builtin_amdgcn_s_barrier();     // all waves' reads of buf[cur] done + DMA visible
    cur ^= 1;
  }
  // epilogue: C write (frag layout col=l16, row=q4*4+i)
#pragma unroll
  for (int mi = 0; mi < 8; ++mi)
#pragma unroll
    for (int ni = 0; ni < 3; ++ni)
#pragma unroll
      for (int i = 0; i < 4; ++i) {
        int m = m0 + wm * 128 + mi * 16 + q4 * 4 + i;
        int n = n0 + wn * 48 + ni * 16 + l16;
        C[(size_t)m * N + n] = (_Float16)acc[mi][ni][i];
      }
}

// ======================= GEMM (2-barrier structure, kept for G2) ==================
// C[M,N] = A[M,K] @ B[N,K]^T, fp16 in, fp32 accum. BMxBN tile, BK=64, 4 waves (2x2).
// Staging via global_load_lds width=16; XOR swizzle applied source-side + read-side.
// XCD-aware 1D swizzled grid: grid = 8 * STRIPE * (M/BM), N/BN == 8*STRIPE.
template <int BM, int BN, int STRIPE, typename OutT>
__global__ __launch_bounds__(256) void gemm_nt_kernel(const _Float16* __restrict__ A,
                                                      const _Float16* __restrict__ B,
                                                      OutT* __restrict__ C,
                                                      int M, int N, int K) {
  constexpr int MI = BM / 32;  // per-wave m-frags (also A stage chunks per wave)
  constexpr int NI = BN / 32;  // per-wave n-frags
  __shared__ _Float16 As[BM * 64];
  __shared__ _Float16 Bs[BN * 64];
  const int tid = threadIdx.x;
  const int wave = tid >> 6, lane = tid & 63;
  const int wm = wave >> 1, wn = wave & 1;
  const int l16 = lane & 15, q4 = lane >> 4;
  const int lrow = lane >> 3, lsc = lane & 7;  // stage: row-in-8, col-chunk

  const int xcd = blockIdx.x & 7;
  const int idx = blockIdx.x >> 3;
  const int n_blk = xcd * STRIPE + idx % STRIPE;
  const int m_blk = idx / STRIPE;
  const int m0 = m_blk * BM, n0 = n_blk * BN;

  f4 acc[MI][NI] = {};

  for (int k0 = 0; k0 < K; k0 += 64) {
    __syncthreads();  // prior iteration's ds_reads done
#pragma unroll
    for (int j = 0; j < MI; ++j) {
      const int row = j * 32 + wave * 8 + lrow;
      gload_lds16(A + (size_t)(m0 + row) * K + k0 + (lsc ^ (row & 7)) * 8,
                  As + j * 2048 + wave * 512);
    }
#pragma unroll
    for (int j = 0; j < NI; ++j) {
      const int row = j * 32 + wave * 8 + lrow;
      gload_lds16(B + (size_t)(n0 + row) * K + k0 + (lsc ^ (row & 7)) * 8,
                  Bs + j * 2048 + wave * 512);
    }
    __syncthreads();  // implicit vmcnt(0) drain; staging visible
#pragma unroll
    for (int ks = 0; ks < 2; ++ks) {
      h8 af[MI], bf[NI];
#pragma unroll
      for (int mi = 0; mi < MI; ++mi) {
        const int row = wm * (BM / 2) + mi * 16 + l16;
        af[mi] = *(const h8*)(As + row * 64 + ((ks * 4 + q4) ^ (row & 7)) * 8);
      }
#pragma unroll
      for (int ni = 0; ni < NI; ++ni) {
        const int row = wn * (BN / 2) + ni * 16 + l16;
        bf[ni] = *(const h8*)(Bs + row * 64 + ((ks * 4 + q4) ^ (row & 7)) * 8);
      }
#pragma unroll
      for (int mi = 0; mi < MI; ++mi)
#pragma unroll
        for (int ni = 0; ni < NI; ++ni)
          acc[mi][ni] = __builtin_amdgcn_mfma_f32_16x16x32_f16(af[mi], bf[ni], acc[mi][ni], 0, 0, 0);
    }
  }
#pragma unroll
  for (int mi = 0; mi < MI; ++mi)
#pragma unroll
    for (int ni = 0; ni < NI; ++ni)
#pragma unroll
      for (int i = 0; i < 4; ++i) {
        int m = m0 + wm * (BM / 2) + mi * 16 + q4 * 4 + i;
        int n = n0 + wn * (BN / 2) + ni * 16 + l16;
        C[(size_t)m * N + n] = (OutT)acc[mi][ni][i];
      }
}

// Fused penalized attention, MFMA-based sigma-prefix (log2 domain), WINDOWED.
// Grid = 1024: qt = 31-(blk>>5), bh low 5. 36 KB LDS, 4 blocks/CU.
__global__ __launch_bounds__(256, 4) void attn_kernel(const _Float16* __restrict__ qkv,
                                                      _Float16* __restrict__ yh) {
  __shared__ _Float16 Qs[64 * 72];   // [qrow][d], pre-scaled by 0.125*log2(e)
  __shared__ _Float16 Ks[64 * 72];   // [krow][d]
  __shared__ _Float16 Vt[64 * 72];   // [d][krow]
  __shared__ _Float16 Ss[64 * 72];   // sigma*log2e, then reused for softmax weights W

  const int tid = threadIdx.x;
  const int wave = tid >> 6, lane = tid & 63;
  const int l16 = lane & 15, q = lane >> 4;
  const int qt = 31 - (blockIdx.x >> 5);
  const int bh = blockIdx.x & 31;
  const int b = bh >> 4, h = bh & 15;
  const size_t base = (size_t)b * 2048 * 3072 + h * 64;
  const int rl = 16 * wave + 4 * q;   // first q-row of this lane's C-layout quad
  const int kt0 = (qt >= 1) ? (qt - 1) : 0;

  // constant B-fragments for prefix matmul: B[n=l16][k = q*8+j]
  h8 Ua, Ub, ONES;
#pragma unroll
  for (int j = 0; j < 8; ++j) {
    int kp = q * 8 + j;
    Ua[j]   = (kp < l16)      ? (_Float16)1.f : (_Float16)0.f;  // strict, cols 0..15 / 32..47
    Ub[j]   = (kp < 16 + l16) ? (_Float16)1.f : (_Float16)0.f;  // strict, cols 16..31 / 48..63
    ONES[j] = (_Float16)1.f;
  }

  // Q tile load (scale = 0.125 * log2(e) -> logits in log2 domain)
  const int srow0 = tid >> 3, sc8 = tid & 7;
  const int srow1 = srow0 + 32;
  {
    const _Float16 qscale = (_Float16)0.18033688f;
    h8 q0 = *(const h8*)(qkv + base + (size_t)(qt * 64 + srow0) * 3072 + sc8 * 8);
    h8 q1 = *(const h8*)(qkv + base + (size_t)(qt * 64 + srow1) * 3072 + sc8 * 8);
    for (int e = 0; e < 8; ++e) { q0[e] = q0[e] * qscale; q1[e] = q1[e] * qscale; }
    *(h8*)(Qs + srow0 * 72 + sc8 * 8) = q0;
    *(h8*)(Qs + srow1 * 72 + sc8 * 8) = q1;
  }

  // prefetch kt=kt0 K/V into registers
  h8 kr0, kr1, vr0, vr1;
  {
    const _Float16* kg = qkv + base + (size_t)kt0 * 64 * 3072 + 1024;
    kr0 = *(const h8*)(kg + (size_t)srow0 * 3072 + sc8 * 8);
    kr1 = *(const h8*)(kg + (size_t)srow1 * 3072 + sc8 * 8);
    const _Float16* vg = qkv + base + (size_t)kt0 * 64 * 3072 + 2048 + lane;
    for (int j = 0; j < 8; ++j) vr0[j] = vg[(size_t)(wave * 16 + j) * 3072];
    for (int j = 0; j < 8; ++j) vr1[j] = vg[(size_t)(wave * 16 + 8 + j) * 3072];
  }

  f4 Oacc[4] = {};
  float m_r[4], l_r[4], c_r[4];
#pragma unroll
  for (int i = 0; i < 4; ++i) { m_r[i] = -1e30f; l_r[i] = 0.f; c_r[i] = 0.f; }

  for (int kt = kt0; kt <= qt; ++kt) {
    __syncthreads();  // B1: prior iteration's LDS reads done
    *(h8*)(Ks + srow0 * 72 + sc8 * 8) = kr0;
    *(h8*)(Ks + srow1 * 72 + sc8 * 8) = kr1;
    *(h8*)(Vt + lane * 72 + wave * 16) = vr0;
    *(h8*)(Vt + lane * 72 + wave * 16 + 8) = vr1;
    __syncthreads();  // B2: staging visible

    if (kt < qt) {  // prefetch kt+1 (consumed at next B1)
      const _Float16* kg = qkv + base + (size_t)(kt + 1) * 64 * 3072 + 1024;
      kr0 = *(const h8*)(kg + (size_t)srow0 * 3072 + sc8 * 8);
      kr1 = *(const h8*)(kg + (size_t)srow1 * 3072 + sc8 * 8);
      const _Float16* vg = qkv + base + (size_t)(kt + 1) * 64 * 3072 + 2048 + lane;
      for (int j = 0; j < 8; ++j) vr0[j] = vg[(size_t)(wave * 16 + j) * 3072];
      for (int j = 0; j < 8; ++j) vr1[j] = vg[(size_t)(wave * 16 + 8 + j) * 3072];
    }
    const bool diag = (kt == qt);

    // P(log2) = Qs @ Ks^T; wave owns q-rows [16w,16w+16): row = rl+i, col = 16ni+l16
    f4 pacc[4] = {};
#pragma unroll
    for (int ks = 0; ks < 2; ++ks) {
      h8 af = *(const h8*)(Qs + (16 * wave + l16) * 72 + ks * 32 + q * 8);
#pragma unroll
      for (int ni = 0; ni < 4; ++ni) {
        h8 bf = *(const h8*)(Ks + (16 * ni + l16) * 72 + ks * 32 + q * 8);
        pacc[ni] = __builtin_amdgcn_mfma_f32_16x16x32_f16(af, bf, pacc[ni], 0, 0, 0);
      }
    }

    // sigma (C-layout) -> LDS (fp16, *log2e); masked on diag tile
#pragma unroll
    for (int ni = 0; ni < 4; ++ni) {
      const int col = 16 * ni + l16;
#pragma unroll
      for (int i = 0; i < 4; ++i) {
        float e = __builtin_amdgcn_exp2f(-pacc[ni][i]);
        float s = __builtin_amdgcn_rcpf(1.f + e) * 1.44269504f;
        if (diag && col > rl + i) s = 0.f;
        Ss[(rl + i) * 72 + col] = (_Float16)s;
      }
    }
    // prefix + totals via MFMA against constant U fragments (wave-private rows)
    f4 ex[4], tot;
    {
      h8 s0 = *(const h8*)(Ss + (16 * wave + l16) * 72 + q * 8);
      h8 s1 = *(const h8*)(Ss + (16 * wave + l16) * 72 + 32 + q * 8);
      f4 z = {};
      f4 t0 = __builtin_amdgcn_mfma_f32_16x16x32_f16(s0, ONES, z, 0, 0, 0);
      ex[0] = __builtin_amdgcn_mfma_f32_16x16x32_f16(s0, Ua, z, 0, 0, 0);
      ex[1] = __builtin_amdgcn_mfma_f32_16x16x32_f16(s0, Ub, z, 0, 0, 0);
      ex[2] = __builtin_amdgcn_mfma_f32_16x16x32_f16(s1, Ua, t0, 0, 0, 0);
      ex[3] = __builtin_amdgcn_mfma_f32_16x16x32_f16(s1, Ub, t0, 0, 0, 0);
      tot   = __builtin_amdgcn_mfma_f32_16x16x32_f16(s1, ONES, t0, 0, 0, 0);
    }
    // L = p + c_r + excl_prefix; row max
    float rmax[4];
#pragma unroll
    for (int i = 0; i < 4; ++i) {
      float L0 = pacc[0][i] + (c_r[i] + ex[0][i]);
      float L1 = pacc[1][i] + (c_r[i] + ex[1][i]);
      float L2 = pacc[2][i] + (c_r[i] + ex[2][i]);
      float L3 = pacc[3][i] + (c_r[i] + ex[3][i]);
      if (diag) {
        if (0  + l16 > rl + i) L0 = -1e30f;
        if (16 + l16 > rl + i) L1 = -1e30f;
        if (32 + l16 > rl + i) L2 = -1e30f;
        if (48 + l16 > rl + i) L3 = -1e30f;
      }
      pacc[0][i] = L0; pacc[1][i] = L1; pacc[2][i] = L2; pacc[3][i] = L3;
      rmax[i] = fmaxf(fmaxf(L0, L1), fmaxf(L2, L3));
      c_r[i] += tot[i];
    }
    float mn[4], al[4];
#pragma unroll
    for (int i = 0; i < 4; ++i) {
      float gm = bcast15(scan16_max(rmax[i]));
      mn[i] = fmaxf(m_r[i], gm);
      al[i] = __builtin_amdgcn_exp2f(m_r[i] - mn[i]);
      m_r[i] = mn[i];
    }
    // weights -> LDS (reuse Ss; same wave-private rows, DS ops in order per wave)
#pragma unroll
    for (int ni = 0; ni < 4; ++ni)
#pragma unroll
      for (int i = 0; i < 4; ++i) {
        float w = __builtin_amdgcn_exp2f(pacc[ni][i] - mn[i]);  // masked: exp2(-huge)=0
        Ss[(rl + i) * 72 + 16 * ni + l16] = (_Float16)w;
      }
#pragma unroll
    for (int ni = 0; ni < 4; ++ni)
#pragma unroll
      for (int i = 0; i < 4; ++i) Oacc[ni][i] *= al[i];
    // O += W @ V ; l-increment via ONES column (row-sum of W, replicated)
    {
      h8 w0 = *(const h8*)(Ss + (16 * wave + l16) * 72 + q * 8);
      h8 w1 = *(const h8*)(Ss + (16 * wave + l16) * 72 + 32 + q * 8);
      f4 z = {};
      f4 la = __builtin_amdgcn_mfma_f32_16x16x32_f16(w0, ONES, z, 0, 0, 0);
      la = __builtin_amdgcn_mfma_f32_16x16x32_f16(w1, ONES, la, 0, 0, 0);
#pragma unroll
      for (int i = 0; i < 4; ++i) l_r[i] = l_r[i] * al[i] + la[i];
#pragma unroll
      for (int ni = 0; ni < 4; ++ni) {
        h8 bf0 = *(const h8*)(Vt + (16 * ni + l16) * 72 + q * 8);
        Oacc[ni] = __builtin_amdgcn_mfma_f32_16x16x32_f16(w0, bf0, Oacc[ni], 0, 0, 0);
        h8 bf1 = *(const h8*)(Vt + (16 * ni + l16) * 72 + 32 + q * 8);
        Oacc[ni] = __builtin_amdgcn_mfma_f32_16x16x32_f16(w1, bf1, Oacc[ni], 0, 0, 0);
      }
    }
  }  // kt

#pragma unroll
  for (int ni = 0; ni < 4; ++ni)
#pragma unroll
    for (int i = 0; i < 4; ++i) {
      int t = qt * 64 + rl + i;
      float yv = Oacc[ni][i] * __builtin_amdgcn_rcpf(l_r[i]);
      yh[((size_t)(b * 2048 + t)) * 1024 + h * 64 + 16 * ni + l16] = (_Float16)yv;
    }
}

extern "C" void kernel_launch(void* const* d_in, const int* in_sizes, int n_in,
                              void* d_out, int out_size, void* d_ws, size_t ws_size,
                              hipStream_t stream) {
  const float* x  = (const float*)d_in[0];   // [2,2048,1024]
  const float* Wa = (const float*)d_in[1];   // [3072,1024]
  const float* Wp = (const float*)d_in[2];   // [1024,1024]
  float* out = (float*)d_out;                // [4096,1024] fp32

  char* ws = (char*)d_ws;
  _Float16* xh   = (_Float16*)(ws);                    //  8 MB
  _Float16* wah  = (_Float16*)(ws + 8388608);          //  6 MB
  _Float16* wph  = (_Float16*)(ws + 14680064);         //  2 MB
  _Float16* qkvh = (_Float16*)(ws + 16777216);         // 24 MB
  _Float16* yh   = (_Float16*)(ws + 41943040);         //  8 MB

  convert_all_kernel<<<8192, 256, 0, stream>>>(x, Wa, Wp, xh, wah, wph);

  // GEMM1 (R14): counted-vmcnt pipeline, 256x192 tile, grid 256 = 1 block/CU.
  gemm1_pipe_kernel<<<256, 512, 0, stream>>>(xh, wah, qkvh, 4096, 3072, 1024);

  attn_kernel<<<1024, 256, 0, stream>>>(qkvh, yh);

  // GEMM2: N/BN = 8 = 8 XCDs x stripe 1; grid = 8*1*64 = 512 (1D, swizzled)
  gemm_nt_kernel<64, 128, 1, float>
      <<<512, 256, 0, stream>>>(yh, wph, out, 4096, 1024, 1024);
}

// Round 7
// 142.390 us; speedup vs baseline: 1.0757x; 1.0757x over previous
//
#include <hip/hip_runtime.h>

// B=2, T=2048, C=1024, H=16, D=64
// qkv row-major [4096, 3072]; y row-major [4096, 1024]; out fp32 [4096,1024]
//
// Time ledger (R11/R12 probes, µs): timed window ~148 = 2 poison fills (~86, harness,
// not optimizable) + conv ~9 + G1 ~30 + attn ~2-3 + G2 ~16 + gaps ~4.
// R13/R14 lessons: G1 schedule rewrites (phase-split, counted vmcnt, 1 block/CU) LOSE
// to the plain 2-barrier 128^2 structure at 3 blocks/CU — cross-block TLP is the
// latency-hider, and at K=1024 (16 K-tiles) ~860 TF is the practical ceiling (m248:
// even full 8-phase stacks land ~850 at K=1024). G1 is reverted and frozen.
// R15 (rerun; prior attempt died to container infra, not the kernel): G2 gets the
// minimal 2-phase double-buffer (stage t+1 issued BEFORE computing t, single drain at
// tile end) — its old loop drained vmcnt right after staging, exposing HBM latency
// every K-tile with only 2 blocks/CU of TLP to cover it.

typedef _Float16 h8 __attribute__((ext_vector_type(8)));
typedef _Float16 h4 __attribute__((ext_vector_type(4)));
typedef float f4 __attribute__((ext_vector_type(4)));

// ---- cross-lane helpers (16-lane DPP rows) ----
template <int CTRL>
__device__ __forceinline__ float dpp_shr_self(float x) {  // shifted-in lanes read own x
  int xi = __builtin_bit_cast(int, x);
  return __builtin_bit_cast(float,
      __builtin_amdgcn_update_dpp(xi, xi, CTRL, 0xF, 0xF, false));
}
__device__ __forceinline__ float scan16_max(float x) {  // inclusive max-scan over 16 lanes
  x = fmaxf(x, dpp_shr_self<0x111>(x));
  x = fmaxf(x, dpp_shr_self<0x112>(x));
  x = fmaxf(x, dpp_shr_self<0x114>(x));
  x = fmaxf(x, dpp_shr_self<0x118>(x));
  return x;
}
__device__ __forceinline__ float bcast15(float x) {  // lane15 of each 16-lane group -> group
  return __builtin_bit_cast(float,
      __builtin_amdgcn_ds_swizzle(__builtin_bit_cast(int, x), 0x01F0));
}

// async global->LDS, 16 B per lane. LDS dest is wave-uniform base + lane*16 (HW rule);
// per-lane GLOBAL address is free, which is how the XOR swizzle is applied (source side).
__device__ __forceinline__ void gload_lds16(const _Float16* src, _Float16* dst_lds) {
  __builtin_amdgcn_global_load_lds(
      (const __attribute__((address_space(1))) void*)src,
      (__attribute__((address_space(3))) void*)dst_lds, 16, 0, 0);
}

// Pin VMEM issue order across this point; ALU/VALU/SALU/MFMA/DS may cross (mask 0x38F).
// Keeps the compiler from sinking the prefetch gloads down to the barrier.
__device__ __forceinline__ void vmem_order_fence() {
  __builtin_amdgcn_sched_barrier(0x38F);
}

// One kernel converts all three fp32 inputs to fp16. Slot = 4 floats.
__global__ __launch_bounds__(256) void convert_all_kernel(const float* __restrict__ x,
                                                          const float* __restrict__ Wa,
                                                          const float* __restrict__ Wp,
                                                          _Float16* __restrict__ xh,
                                                          _Float16* __restrict__ wah,
                                                          _Float16* __restrict__ wph) {
  int i = blockIdx.x * 256 + threadIdx.x;
  const float* src;
  _Float16* dst;
  int off;
  if (i < 1048576) { src = x; dst = xh; off = i; }
  else if (i < 1048576 + 786432) { src = Wa; dst = wah; off = i - 1048576; }
  else { src = Wp; dst = wph; off = i - (1048576 + 786432); }
  f4 v = *(const f4*)(src + (size_t)off * 4);
  h4 o;
  for (int j = 0; j < 4; ++j) o[j] = (_Float16)v[j];
  *(h4*)(dst + (size_t)off * 4) = o;
}

// ================== GEMM1 (frozen): 2-barrier 128x128, 3 blocks/CU =================
// C[M,N] = A[M,K] @ B[N,K]^T, fp16 in, fp32 accum. BK=64, 4 waves (2x2).
// Staging via global_load_lds width=16; XOR swizzle applied source-side + read-side.
// XCD-aware 1D swizzled grid: grid = 8 * STRIPE * (M/BM), N/BN == 8*STRIPE.
template <int BM, int BN, int STRIPE, typename OutT>
__global__ __launch_bounds__(256) void gemm_nt_kernel(const _Float16* __restrict__ A,
                                                      const _Float16* __restrict__ B,
                                                      OutT* __restrict__ C,
                                                      int M, int N, int K) {
  constexpr int MI = BM / 32;  // per-wave m-frags (also A stage chunks per wave)
  constexpr int NI = BN / 32;  // per-wave n-frags
  __shared__ _Float16 As[BM * 64];
  __shared__ _Float16 Bs[BN * 64];
  const int tid = threadIdx.x;
  const int wave = tid >> 6, lane = tid & 63;
  const int wm = wave >> 1, wn = wave & 1;
  const int l16 = lane & 15, q4 = lane >> 4;
  const int lrow = lane >> 3, lsc = lane & 7;  // stage: row-in-8, col-chunk

  const int xcd = blockIdx.x & 7;
  const int idx = blockIdx.x >> 3;
  const int n_blk = xcd * STRIPE + idx % STRIPE;
  const int m_blk = idx / STRIPE;
  const int m0 = m_blk * BM, n0 = n_blk * BN;

  f4 acc[MI][NI] = {};

  for (int k0 = 0; k0 < K; k0 += 64) {
    __syncthreads();  // prior iteration's ds_reads done
#pragma unroll
    for (int j = 0; j < MI; ++j) {
      const int row = j * 32 + wave * 8 + lrow;
      gload_lds16(A + (size_t)(m0 + row) * K + k0 + (lsc ^ (row & 7)) * 8,
                  As + j * 2048 + wave * 512);
    }
#pragma unroll
    for (int j = 0; j < NI; ++j) {
      const int row = j * 32 + wave * 8 + lrow;
      gload_lds16(B + (size_t)(n0 + row) * K + k0 + (lsc ^ (row & 7)) * 8,
                  Bs + j * 2048 + wave * 512);
    }
    __syncthreads();  // implicit vmcnt(0) drain; staging visible
#pragma unroll
    for (int ks = 0; ks < 2; ++ks) {
      h8 af[MI], bf[NI];
#pragma unroll
      for (int mi = 0; mi < MI; ++mi) {
        const int row = wm * (BM / 2) + mi * 16 + l16;
        af[mi] = *(const h8*)(As + row * 64 + ((ks * 4 + q4) ^ (row & 7)) * 8);
      }
#pragma unroll
      for (int ni = 0; ni < NI; ++ni) {
        const int row = wn * (BN / 2) + ni * 16 + l16;
        bf[ni] = *(const h8*)(Bs + row * 64 + ((ks * 4 + q4) ^ (row & 7)) * 8);
      }
#pragma unroll
      for (int mi = 0; mi < MI; ++mi)
#pragma unroll
        for (int ni = 0; ni < NI; ++ni)
          acc[mi][ni] = __builtin_amdgcn_mfma_f32_16x16x32_f16(af[mi], bf[ni], acc[mi][ni], 0, 0, 0);
    }
  }
#pragma unroll
  for (int mi = 0; mi < MI; ++mi)
#pragma unroll
    for (int ni = 0; ni < NI; ++ni)
#pragma unroll
      for (int i = 0; i < 4; ++i) {
        int m = m0 + wm * (BM / 2) + mi * 16 + q4 * 4 + i;
        int n = n0 + wn * (BN / 2) + ni * 16 + l16;
        C[(size_t)m * N + n] = (OutT)acc[mi][ni][i];
      }
}

// ============== GEMM2 (R15): 2-phase double-buffered 64x128, 2 blocks/CU ===========
// Same fragment/swizzle math as gemm_nt_kernel<64,128,1>, but stage of K-tile t+1 is
// issued BEFORE computing tile t; the single __syncthreads at tile end both drains the
// DMA (vmcnt 0) and fences the buffer swap. Stage latency hides under 32 MFMAs.
// LDS 48 KB (2 buffers) -> still 2 blocks/CU at grid 512.
__global__ __launch_bounds__(256) void gemm2_dbuf_kernel(const _Float16* __restrict__ A,
                                                         const _Float16* __restrict__ B,
                                                         float* __restrict__ C,
                                                         int M, int N, int K) {
  constexpr int MI = 2, NI = 4;   // BM=64, BN=128
  __shared__ _Float16 As[2][64 * 64];    // 16 KB
  __shared__ _Float16 Bs[2][128 * 64];   // 32 KB
  const int tid = threadIdx.x;
  const int wave = tid >> 6, lane = tid & 63;
  const int wm = wave >> 1, wn = wave & 1;
  const int l16 = lane & 15, q4 = lane >> 4;
  const int lrow = lane >> 3, lsc = lane & 7;

  const int xcd = blockIdx.x & 7;
  const int idx = blockIdx.x >> 3;
  const int n_blk = xcd;          // STRIPE = 1 (N/BN = 8)
  const int m_blk = idx;
  const int m0 = m_blk * 64, n0 = n_blk * 128;

  f4 acc[MI][NI] = {};

  auto stage = [&](int buf, int k0) {
#pragma unroll
    for (int j = 0; j < MI; ++j) {
      const int row = j * 32 + wave * 8 + lrow;
      gload_lds16(A + (size_t)(m0 + row) * K + k0 + (lsc ^ (row & 7)) * 8,
                  &As[buf][(j * 32 + wave * 8) * 64]);
    }
#pragma unroll
    for (int j = 0; j < NI; ++j) {
      const int row = j * 32 + wave * 8 + lrow;
      gload_lds16(B + (size_t)(n0 + row) * K + k0 + (lsc ^ (row & 7)) * 8,
                  &Bs[buf][(j * 32 + wave * 8) * 64]);
    }
  };

  stage(0, 0);
  __syncthreads();  // drain prologue DMA; buffer 0 visible
  int cur = 0;
  for (int k0 = 0; k0 < K; k0 += 64) {
    if (k0 + 64 < K) {  // issue next tile's stage; waited at the trailing barrier
      stage(cur ^ 1, k0 + 64);
      vmem_order_fence();  // keep the gloads issued up here, ahead of the MFMA block
    }
#pragma unroll
    for (int ks = 0; ks < 2; ++ks) {
      h8 af[MI], bf[NI];
#pragma unroll
      for (int mi = 0; mi < MI; ++mi) {
        const int row = wm * 32 + mi * 16 + l16;
        af[mi] = *(const h8*)(&As[cur][row * 64 + ((ks * 4 + q4) ^ (row & 7)) * 8]);
      }
#pragma unroll
      for (int ni = 0; ni < NI; ++ni) {
        const int row = wn * 64 + ni * 16 + l16;
        bf[ni] = *(const h8*)(&Bs[cur][row * 64 + ((ks * 4 + q4) ^ (row & 7)) * 8]);
      }
#pragma unroll
      for (int mi = 0; mi < MI; ++mi)
#pragma unroll
        for (int ni = 0; ni < NI; ++ni)
          acc[mi][ni] = __builtin_amdgcn_mfma_f32_16x16x32_f16(af[mi], bf[ni], acc[mi][ni], 0, 0, 0);
    }
    __syncthreads();  // drains next-tile DMA (vmcnt 0) + all waves done reading cur
    cur ^= 1;
  }
#pragma unroll
  for (int mi = 0; mi < MI; ++mi)
#pragma unroll
    for (int ni = 0; ni < NI; ++ni)
#pragma unroll
      for (int i = 0; i < 4; ++i) {
        int m = m0 + wm * 32 + mi * 16 + q4 * 4 + i;
        int n = n0 + wn * 64 + ni * 16 + l16;
        C[(size_t)m * N + n] = acc[mi][ni][i];
      }
}

// Fused penalized attention, MFMA-based sigma-prefix (log2 domain), WINDOWED.
// Grid = 1024: qt = 31-(blk>>5), bh low 5. 36 KB LDS, 4 blocks/CU.
__global__ __launch_bounds__(256, 4) void attn_kernel(const _Float16* __restrict__ qkv,
                                                      _Float16* __restrict__ yh) {
  __shared__ _Float16 Qs[64 * 72];   // [qrow][d], pre-scaled by 0.125*log2(e)
  __shared__ _Float16 Ks[64 * 72];   // [krow][d]
  __shared__ _Float16 Vt[64 * 72];   // [d][krow]
  __shared__ _Float16 Ss[64 * 72];   // sigma*log2e, then reused for softmax weights W

  const int tid = threadIdx.x;
  const int wave = tid >> 6, lane = tid & 63;
  const int l16 = lane & 15, q = lane >> 4;
  const int qt = 31 - (blockIdx.x >> 5);
  const int bh = blockIdx.x & 31;
  const int b = bh >> 4, h = bh & 15;
  const size_t base = (size_t)b * 2048 * 3072 + h * 64;
  const int rl = 16 * wave + 4 * q;   // first q-row of this lane's C-layout quad
  const int kt0 = (qt >= 1) ? (qt - 1) : 0;

  // constant B-fragments for prefix matmul: B[n=l16][k = q*8+j]
  h8 Ua, Ub, ONES;
#pragma unroll
  for (int j = 0; j < 8; ++j) {
    int kp = q * 8 + j;
    Ua[j]   = (kp < l16)      ? (_Float16)1.f : (_Float16)0.f;  // strict, cols 0..15 / 32..47
    Ub[j]   = (kp < 16 + l16) ? (_Float16)1.f : (_Float16)0.f;  // strict, cols 16..31 / 48..63
    ONES[j] = (_Float16)1.f;
  }

  // Q tile load (scale = 0.125 * log2(e) -> logits in log2 domain)
  const int srow0 = tid >> 3, sc8 = tid & 7;
  const int srow1 = srow0 + 32;
  {
    const _Float16 qscale = (_Float16)0.18033688f;
    h8 q0 = *(const h8*)(qkv + base + (size_t)(qt * 64 + srow0) * 3072 + sc8 * 8);
    h8 q1 = *(const h8*)(qkv + base + (size_t)(qt * 64 + srow1) * 3072 + sc8 * 8);
    for (int e = 0; e < 8; ++e) { q0[e] = q0[e] * qscale; q1[e] = q1[e] * qscale; }
    *(h8*)(Qs + srow0 * 72 + sc8 * 8) = q0;
    *(h8*)(Qs + srow1 * 72 + sc8 * 8) = q1;
  }

  // prefetch kt=kt0 K/V into registers
  h8 kr0, kr1, vr0, vr1;
  {
    const _Float16* kg = qkv + base + (size_t)kt0 * 64 * 3072 + 1024;
    kr0 = *(const h8*)(kg + (size_t)srow0 * 3072 + sc8 * 8);
    kr1 = *(const h8*)(kg + (size_t)srow1 * 3072 + sc8 * 8);
    const _Float16* vg = qkv + base + (size_t)kt0 * 64 * 3072 + 2048 + lane;
    for (int j = 0; j < 8; ++j) vr0[j] = vg[(size_t)(wave * 16 + j) * 3072];
    for (int j = 0; j < 8; ++j) vr1[j] = vg[(size_t)(wave * 16 + 8 + j) * 3072];
  }

  f4 Oacc[4] = {};
  float m_r[4], l_r[4], c_r[4];
#pragma unroll
  for (int i = 0; i < 4; ++i) { m_r[i] = -1e30f; l_r[i] = 0.f; c_r[i] = 0.f; }

  for (int kt = kt0; kt <= qt; ++kt) {
    __syncthreads();  // B1: prior iteration's LDS reads done
    *(h8*)(Ks + srow0 * 72 + sc8 * 8) = kr0;
    *(h8*)(Ks + srow1 * 72 + sc8 * 8) = kr1;
    *(h8*)(Vt + lane * 72 + wave * 16) = vr0;
    *(h8*)(Vt + lane * 72 + wave * 16 + 8) = vr1;
    __syncthreads();  // B2: staging visible

    if (kt < qt) {  // prefetch kt+1 (consumed at next B1)
      const _Float16* kg = qkv + base + (size_t)(kt + 1) * 64 * 3072 + 1024;
      kr0 = *(const h8*)(kg + (size_t)srow0 * 3072 + sc8 * 8);
      kr1 = *(const h8*)(kg + (size_t)srow1 * 3072 + sc8 * 8);
      const _Float16* vg = qkv + base + (size_t)(kt + 1) * 64 * 3072 + 2048 + lane;
      for (int j = 0; j < 8; ++j) vr0[j] = vg[(size_t)(wave * 16 + j) * 3072];
      for (int j = 0; j < 8; ++j) vr1[j] = vg[(size_t)(wave * 16 + 8 + j) * 3072];
    }
    const bool diag = (kt == qt);

    // P(log2) = Qs @ Ks^T; wave owns q-rows [16w,16w+16): row = rl+i, col = 16ni+l16
    f4 pacc[4] = {};
#pragma unroll
    for (int ks = 0; ks < 2; ++ks) {
      h8 af = *(const h8*)(Qs + (16 * wave + l16) * 72 + ks * 32 + q * 8);
#pragma unroll
      for (int ni = 0; ni < 4; ++ni) {
        h8 bf = *(const h8*)(Ks + (16 * ni + l16) * 72 + ks * 32 + q * 8);
        pacc[ni] = __builtin_amdgcn_mfma_f32_16x16x32_f16(af, bf, pacc[ni], 0, 0, 0);
      }
    }

    // sigma (C-layout) -> LDS (fp16, *log2e); masked on diag tile
#pragma unroll
    for (int ni = 0; ni < 4; ++ni) {
      const int col = 16 * ni + l16;
#pragma unroll
      for (int i = 0; i < 4; ++i) {
        float e = __builtin_amdgcn_exp2f(-pacc[ni][i]);
        float s = __builtin_amdgcn_rcpf(1.f + e) * 1.44269504f;
        if (diag && col > rl + i) s = 0.f;
        Ss[(rl + i) * 72 + col] = (_Float16)s;
      }
    }
    // prefix + totals via MFMA against constant U fragments (wave-private rows)
    f4 ex[4], tot;
    {
      h8 s0 = *(const h8*)(Ss + (16 * wave + l16) * 72 + q * 8);
      h8 s1 = *(const h8*)(Ss + (16 * wave + l16) * 72 + 32 + q * 8);
      f4 z = {};
      f4 t0 = __builtin_amdgcn_mfma_f32_16x16x32_f16(s0, ONES, z, 0, 0, 0);
      ex[0] = __builtin_amdgcn_mfma_f32_16x16x32_f16(s0, Ua, z, 0, 0, 0);
      ex[1] = __builtin_amdgcn_mfma_f32_16x16x32_f16(s0, Ub, z, 0, 0, 0);
      ex[2] = __builtin_amdgcn_mfma_f32_16x16x32_f16(s1, Ua, t0, 0, 0, 0);
      ex[3] = __builtin_amdgcn_mfma_f32_16x16x32_f16(s1, Ub, t0, 0, 0, 0);
      tot   = __builtin_amdgcn_mfma_f32_16x16x32_f16(s1, ONES, t0, 0, 0, 0);
    }
    // L = p + c_r + excl_prefix; row max
    float rmax[4];
#pragma unroll
    for (int i = 0; i < 4; ++i) {
      float L0 = pacc[0][i] + (c_r[i] + ex[0][i]);
      float L1 = pacc[1][i] + (c_r[i] + ex[1][i]);
      float L2 = pacc[2][i] + (c_r[i] + ex[2][i]);
      float L3 = pacc[3][i] + (c_r[i] + ex[3][i]);
      if (diag) {
        if (0  + l16 > rl + i) L0 = -1e30f;
        if (16 + l16 > rl + i) L1 = -1e30f;
        if (32 + l16 > rl + i) L2 = -1e30f;
        if (48 + l16 > rl + i) L3 = -1e30f;
      }
      pacc[0][i] = L0; pacc[1][i] = L1; pacc[2][i] = L2; pacc[3][i] = L3;
      rmax[i] = fmaxf(fmaxf(L0, L1), fmaxf(L2, L3));
      c_r[i] += tot[i];
    }
    float mn[4], al[4];
#pragma unroll
    for (int i = 0; i < 4; ++i) {
      float gm = bcast15(scan16_max(rmax[i]));
      mn[i] = fmaxf(m_r[i], gm);
      al[i] = __builtin_amdgcn_exp2f(m_r[i] - mn[i]);
      m_r[i] = mn[i];
    }
    // weights -> LDS (reuse Ss; same wave-private rows, DS ops in order per wave)
#pragma unroll
    for (int ni = 0; ni < 4; ++ni)
#pragma unroll
      for (int i = 0; i < 4; ++i) {
        float w = __builtin_amdgcn_exp2f(pacc[ni][i] - mn[i]);  // masked: exp2(-huge)=0
        Ss[(rl + i) * 72 + 16 * ni + l16] = (_Float16)w;
      }
#pragma unroll
    for (int ni = 0; ni < 4; ++ni)
#pragma unroll
      for (int i = 0; i < 4; ++i) Oacc[ni][i] *= al[i];
    // O += W @ V ; l-increment via ONES column (row-sum of W, replicated)
    {
      h8 w0 = *(const h8*)(Ss + (16 * wave + l16) * 72 + q * 8);
      h8 w1 = *(const h8*)(Ss + (16 * wave + l16) * 72 + 32 + q * 8);
      f4 z = {};
      f4 la = __builtin_amdgcn_mfma_f32_16x16x32_f16(w0, ONES, z, 0, 0, 0);
      la = __builtin_amdgcn_mfma_f32_16x16x32_f16(w1, ONES, la, 0, 0, 0);
#pragma unroll
      for (int i = 0; i < 4; ++i) l_r[i] = l_r[i] * al[i] + la[i];
#pragma unroll
      for (int ni = 0; ni < 4; ++ni) {
        h8 bf0 = *(const h8*)(Vt + (16 * ni + l16) * 72 + q * 8);
        Oacc[ni] = __builtin_amdgcn_mfma_f32_16x16x32_f16(w0, bf0, Oacc[ni], 0, 0, 0);
        h8 bf1 = *(const h8*)(Vt + (16 * ni + l16) * 72 + 32 + q * 8);
        Oacc[ni] = __builtin_amdgcn_mfma_f32_16x16x32_f16(w1, bf1, Oacc[ni], 0, 0, 0);
      }
    }
  }  // kt

#pragma unroll
  for (int ni = 0; ni < 4; ++ni)
#pragma unroll
    for (int i = 0; i < 4; ++i) {
      int t = qt * 64 + rl + i;
      float yv = Oacc[ni][i] * __builtin_amdgcn_rcpf(l_r[i]);
      yh[((size_t)(b * 2048 + t)) * 1024 + h * 64 + 16 * ni + l16] = (_Float16)yv;
    }
}

extern "C" void kernel_launch(void* const* d_in, const int* in_sizes, int n_in,
                              void* d_out, int out_size, void* d_ws, size_t ws_size,
                              hipStream_t stream) {
  const float* x  = (const float*)d_in[0];   // [2,2048,1024]
  const float* Wa = (const float*)d_in[1];   // [3072,1024]
  const float* Wp = (const float*)d_in[2];   // [1024,1024]
  float* out = (float*)d_out;                // [4096,1024] fp32

  char* ws = (char*)d_ws;
  _Float16* xh   = (_Float16*)(ws);                    //  8 MB
  _Float16* wah  = (_Float16*)(ws + 8388608);          //  6 MB
  _Float16* wph  = (_Float16*)(ws + 14680064);         //  2 MB
  _Float16* qkvh = (_Float16*)(ws + 16777216);         // 24 MB
  _Float16* yh   = (_Float16*)(ws + 41943040);         //  8 MB

  convert_all_kernel<<<8192, 256, 0, stream>>>(x, Wa, Wp, xh, wah, wph);

  // GEMM1 (frozen): N/BN = 24 = 8 XCDs x stripe 3; grid = 8*3*32 = 768 (1D, swizzled)
  gemm_nt_kernel<128, 128, 3, _Float16>
      <<<768, 256, 0, stream>>>(xh, wah, qkvh, 4096, 3072, 1024);

  attn_kernel<<<1024, 256, 0, stream>>>(qkvh, yh);

  // GEMM2 (R15): 2-phase dbuf 64x128; grid = 8*64 = 512 (2 blocks/CU)
  gemm2_dbuf_kernel<<<512, 256, 0, stream>>>(yh, wph, out, 4096, 1024, 1024);
}